// Round 3
// baseline (496.091 us; speedup 1.0000x reference)
//
#include <hip/hip_runtime.h>
#include <hip/hip_bf16.h>

// CrossAttentionLayer on MI355X (gfx950), round 3.
// Round-3 change: GEMMs rewritten with counted-vmcnt phase-split schedule
// (T3+T4), setprio around MFMA clusters (T5), XCD-aware block swizzle (T1).
//   gemm256: 256x256 tile, 8 waves, 2 phases/K-tile  -> W1 (N=4096)
//   gemm128: 128x128 tile, 4 waves, 2 phases/K-tile  -> Q,K,V,Wo,W2 (N=1024)
// Schedule ledger (both): issue order per K-tile [A0,A2,B0,B1 | B2,B3,A1,A3],
// P1 consumes A-half0+B-all -> vmcnt(2); P2 consumes A-half1 -> vmcnt(4)
// (vmcnt(0) only on the final peeled iteration). Attention/LN unchanged (r2).

typedef __bf16 bf16x8 __attribute__((ext_vector_type(8)));
typedef __bf16 bf16x4 __attribute__((ext_vector_type(4)));
typedef float f32x4 __attribute__((ext_vector_type(4)));

#define DEV static __device__ __forceinline__

DEV short f2bf(float x) {  // RNE float->bf16
  union { float f; unsigned u; } c; c.f = x;
  unsigned r = c.u + 0x7fffu + ((c.u >> 16) & 1u);
  return (short)(r >> 16);
}

DEV void gload_lds16(const void* g, void* l) {
  __builtin_amdgcn_global_load_lds((__attribute__((address_space(1))) void*)g,
                                   (__attribute__((address_space(3))) void*)l, 16, 0, 0);
}

// ---------------------------------------------------------------- transpose
__launch_bounds__(256, 4)
__global__ void transpose_f32_bf16(const float* __restrict__ in, short* __restrict__ outT,
                                   int R, int C) {
  __shared__ float t[32][33];
  const int c0 = blockIdx.x * 32, r0 = blockIdx.y * 32;
  const int tx = threadIdx.x, ty = threadIdx.y;
#pragma unroll
  for (int i = 0; i < 4; ++i)
    t[ty + 8 * i][tx] = in[(size_t)(r0 + ty + 8 * i) * C + (c0 + tx)];
  __syncthreads();
#pragma unroll
  for (int i = 0; i < 4; ++i)
    outT[(size_t)(c0 + ty + 8 * i) * R + (r0 + tx)] = f2bf(t[tx][ty + 8 * i]);
}

// V [B*2048][1024](bf16) -> Vt [bh][64][2048](bf16)
__launch_bounds__(256, 4)
__global__ void transpose_v(const short* __restrict__ V, short* __restrict__ Vt) {
  __shared__ short t[32][33];
  const int m0 = blockIdx.x * 32;
  const int d0 = blockIdx.y * 32;
  const int bh = blockIdx.z;
  const int b = bh >> 4, h = bh & 15;
  const int tx = threadIdx.x, ty = threadIdx.y;
#pragma unroll
  for (int i = 0; i < 4; ++i)
    t[ty + 8 * i][tx] = V[((size_t)b * 2048 + m0 + ty + 8 * i) * 1024 + h * 64 + d0 + tx];
  __syncthreads();
#pragma unroll
  for (int i = 0; i < 4; ++i)
    Vt[((size_t)bh * 64 + d0 + ty + 8 * i) * 2048 + (m0 + tx)] = t[tx][ty + 8 * i];
}

// ---------------------------------------------------------------- layernorm
__launch_bounds__(256, 4)
__global__ void ln_kernel(const float* __restrict__ in, const float* __restrict__ g,
                          const float* __restrict__ b, short* __restrict__ out) {
  const int row = blockIdx.x;
  const int tid = threadIdx.x;
  const float4 v = ((const float4*)(in + (size_t)row * 1024))[tid];
  float s = v.x + v.y + v.z + v.w;
  float s2 = v.x * v.x + v.y * v.y + v.z * v.z + v.w * v.w;
#pragma unroll
  for (int off = 1; off < 64; off <<= 1) {
    s += __shfl_xor(s, off);
    s2 += __shfl_xor(s2, off);
  }
  __shared__ float ps[4], pq[4];
  const int w = tid >> 6, lane = tid & 63;
  if (lane == 0) { ps[w] = s; pq[w] = s2; }
  __syncthreads();
  s = ps[0] + ps[1] + ps[2] + ps[3];
  s2 = pq[0] + pq[1] + pq[2] + pq[3];
  const float mu = s * (1.f / 1024.f);
  const float rs = rsqrtf(s2 * (1.f / 1024.f) - mu * mu + 1e-5f);
  const float4 gg = ((const float4*)g)[tid];
  const float4 bb = ((const float4*)b)[tid];
  short4 o4;
  o4.x = f2bf((v.x - mu) * rs * gg.x + bb.x);
  o4.y = f2bf((v.y - mu) * rs * gg.y + bb.y);
  o4.z = f2bf((v.z - mu) * rs * gg.z + bb.z);
  o4.w = f2bf((v.w - mu) * rs * gg.w + bb.w);
  ((short4*)(out + (size_t)row * 1024))[tid] = o4;
}

// ---------------------------------------------------------------- GEMM
enum { EPI_Q = 0, EPI_PLAIN = 1, EPI_BIAS_RESID_F32 = 2, EPI_BIAS_SILU = 3 };

DEV void epi_store(int EPI, size_t idx, int cg, float v, const float* bias,
                   const float* resid, float scale, short* outb, float* outf) {
  if (EPI == EPI_Q) {
    outb[idx] = f2bf(v * scale);
  } else if (EPI == EPI_PLAIN) {
    outb[idx] = f2bf(v);
  } else if (EPI == EPI_BIAS_RESID_F32) {
    outf[idx] = v + bias[cg] + resid[idx];
  } else {
    const float u = v + bias[cg];
    outb[idx] = f2bf(u / (1.f + __expf(-u)));
  }
}

// ---- gemm256: BM=BN=256, BK=64, 512 thr (8 waves 2x4), per-wave 128x64.
template <int EPI>
__launch_bounds__(512, 2)
__global__ void gemm256(const short* __restrict__ A, const short* __restrict__ Bt,
                        int N, int K, int nbx, const float* __restrict__ bias,
                        const float* __restrict__ resid, float scale,
                        short* __restrict__ outb, float* __restrict__ outf) {
  __shared__ short Al[2][256 * 64];
  __shared__ short Bl[2][256 * 64];
  const int tid = threadIdx.x;
  const int lane = tid & 63, w = tid >> 6;
  const int wrow = w >> 2, wcol = w & 3;
  const int lg = lane >> 4, lr = lane & 15;

  const int nwg = gridDim.x;
  const int id = blockIdx.x;
  const int swz = (id & 7) * (nwg >> 3) + (id >> 3);  // nwg % 8 == 0 (bijective)
  const int bx = swz % nbx, by = swz / nbx;
  const int row0 = by * 256, col0 = bx * 256;

  const size_t AROW = (size_t)K * 2;  // bytes per row
  const int srow8 = lane >> 3;
  const int scb = ((lane & 7) << 4) ^ (srow8 << 4);  // pre-swizzled source col-byte
  const char* Asrc = (const char*)A + (size_t)(row0 + w * 8 + srow8) * AROW + scb;
  const char* Bsrc = (const char*)Bt + (size_t)(col0 + w * 8 + srow8) * AROW + scb;
  const int ldst = (w * 8) * 128;
  const int rsw = (lr & 7) << 4;
  const int KT = K >> 6;

#define ISS_A(i, kt, b) gload_lds16(Asrc + (size_t)((i) * 64) * AROW + (size_t)(kt) * 128, \
                                    (char*)&Al[b][0] + ((i) * 64) * 128 + ldst)
#define ISS_B(i, kt, b) gload_lds16(Bsrc + (size_t)((i) * 64) * AROW + (size_t)(kt) * 128, \
                                    (char*)&Bl[b][0] + ((i) * 64) * 128 + ldst)

  // prologue: tile 0 in steady-state order
  ISS_A(0, 0, 0); ISS_A(2, 0, 0); ISS_B(0, 0, 0); ISS_B(1, 0, 0);
  ISS_B(2, 0, 0); ISS_B(3, 0, 0); ISS_A(1, 0, 0); ISS_A(3, 0, 0);

  f32x4 acc[8][4] = {};
  int bufc = 0;
  for (int kt = 0; kt < KT; ++kt) {
    const bool pref = (kt + 1 < KT);
    const int nb = bufc ^ 1;
    bf16x8 af[4][2], bfr[4][2];
    // ---------------- Phase 1: M-half 0, all N
    __builtin_amdgcn_sched_barrier(0);
    asm volatile("s_waitcnt vmcnt(2)" ::: "memory");
    __builtin_amdgcn_s_barrier();
    __builtin_amdgcn_sched_barrier(0);
    if (pref) { ISS_A(0, kt + 1, nb); ISS_A(2, kt + 1, nb); ISS_B(0, kt + 1, nb); ISS_B(1, kt + 1, nb); }
#pragma unroll
    for (int ni = 0; ni < 4; ++ni) {
      const int r = wcol * 64 + ni * 16 + lr;
#pragma unroll
      for (int ks = 0; ks < 2; ++ks)
        bfr[ni][ks] = *(const bf16x8*)((const char*)&Bl[bufc][0] + r * 128 + ((ks * 64 + lg * 16) ^ rsw));
    }
#pragma unroll
    for (int mq = 0; mq < 4; ++mq) {
      const int r = wrow * 128 + mq * 16 + lr;
#pragma unroll
      for (int ks = 0; ks < 2; ++ks)
        af[mq][ks] = *(const bf16x8*)((const char*)&Al[bufc][0] + r * 128 + ((ks * 64 + lg * 16) ^ rsw));
    }
    __builtin_amdgcn_s_setprio(1);
#pragma unroll
    for (int mq = 0; mq < 4; ++mq)
#pragma unroll
      for (int ni = 0; ni < 4; ++ni)
#pragma unroll
        for (int ks = 0; ks < 2; ++ks)
          acc[mq][ni] = __builtin_amdgcn_mfma_f32_16x16x32_bf16(af[mq][ks], bfr[ni][ks], acc[mq][ni], 0, 0, 0);
    __builtin_amdgcn_s_setprio(0);
    // ---------------- Phase 2: M-half 1, all N (B frags reused from regs)
    __builtin_amdgcn_sched_barrier(0);
    if (pref) asm volatile("s_waitcnt vmcnt(4)" ::: "memory");
    else      asm volatile("s_waitcnt vmcnt(0)" ::: "memory");
    __builtin_amdgcn_s_barrier();
    __builtin_amdgcn_sched_barrier(0);
    if (pref) { ISS_B(2, kt + 1, nb); ISS_B(3, kt + 1, nb); ISS_A(1, kt + 1, nb); ISS_A(3, kt + 1, nb); }
#pragma unroll
    for (int mq = 0; mq < 4; ++mq) {
      const int r = wrow * 128 + 64 + mq * 16 + lr;
#pragma unroll
      for (int ks = 0; ks < 2; ++ks)
        af[mq][ks] = *(const bf16x8*)((const char*)&Al[bufc][0] + r * 128 + ((ks * 64 + lg * 16) ^ rsw));
    }
    __builtin_amdgcn_s_setprio(1);
#pragma unroll
    for (int mq = 0; mq < 4; ++mq)
#pragma unroll
      for (int ni = 0; ni < 4; ++ni)
#pragma unroll
        for (int ks = 0; ks < 2; ++ks)
          acc[4 + mq][ni] = __builtin_amdgcn_mfma_f32_16x16x32_bf16(af[mq][ks], bfr[ni][ks], acc[4 + mq][ni], 0, 0, 0);
    __builtin_amdgcn_s_setprio(0);
    bufc ^= 1;
  }
#undef ISS_A
#undef ISS_B
#pragma unroll
  for (int mi = 0; mi < 8; ++mi) {
#pragma unroll
    for (int ni = 0; ni < 4; ++ni) {
      const int cg = col0 + wcol * 64 + ni * 16 + lr;
#pragma unroll
      for (int r = 0; r < 4; ++r) {
        const int rg = row0 + wrow * 128 + mi * 16 + lg * 4 + r;
        epi_store(EPI, (size_t)rg * N + cg, cg, acc[mi][ni][r], bias, resid, scale, outb, outf);
      }
    }
  }
}

// ---- gemm128: BM=BN=128, BK=64, 256 thr (4 waves 2x2), per-wave 64x64.
template <int EPI>
__launch_bounds__(256, 2)
__global__ void gemm128(const short* __restrict__ A, const short* __restrict__ Bt,
                        int N, int K, int nbx, const float* __restrict__ bias,
                        const float* __restrict__ resid, float scale,
                        short* __restrict__ outb, float* __restrict__ outf) {
  __shared__ short Al[2][128 * 64];
  __shared__ short Bl[2][128 * 64];
  const int tid = threadIdx.x;
  const int lane = tid & 63, w = tid >> 6;
  const int wrow = w >> 1, wcol = w & 1;
  const int lg = lane >> 4, lr = lane & 15;

  const int nwg = gridDim.x;
  const int id = blockIdx.x;
  const int swz = (id & 7) * (nwg >> 3) + (id >> 3);
  const int bx = swz % nbx, by = swz / nbx;
  const int row0 = by * 128, col0 = bx * 128;

  const size_t AROW = (size_t)K * 2;
  const int srow8 = lane >> 3;
  const int scb = ((lane & 7) << 4) ^ (srow8 << 4);
  const char* Asrc = (const char*)A + (size_t)(row0 + w * 8 + srow8) * AROW + scb;
  const char* Bsrc = (const char*)Bt + (size_t)(col0 + w * 8 + srow8) * AROW + scb;
  const int ldst = (w * 8) * 128;
  const int rsw = (lr & 7) << 4;
  const int KT = K >> 6;

#define ISS_A(i, kt, b) gload_lds16(Asrc + (size_t)((i) * 32) * AROW + (size_t)(kt) * 128, \
                                    (char*)&Al[b][0] + ((i) * 32) * 128 + ldst)
#define ISS_B(i, kt, b) gload_lds16(Bsrc + (size_t)((i) * 32) * AROW + (size_t)(kt) * 128, \
                                    (char*)&Bl[b][0] + ((i) * 32) * 128 + ldst)

  ISS_A(0, 0, 0); ISS_A(2, 0, 0); ISS_B(0, 0, 0); ISS_B(1, 0, 0);
  ISS_B(2, 0, 0); ISS_B(3, 0, 0); ISS_A(1, 0, 0); ISS_A(3, 0, 0);

  f32x4 acc[4][4] = {};
  int bufc = 0;
  for (int kt = 0; kt < KT; ++kt) {
    const bool pref = (kt + 1 < KT);
    const int nb = bufc ^ 1;
    bf16x8 af[2][2], bfr[4][2];
    // ---------------- Phase 1: M-half 0
    __builtin_amdgcn_sched_barrier(0);
    asm volatile("s_waitcnt vmcnt(2)" ::: "memory");
    __builtin_amdgcn_s_barrier();
    __builtin_amdgcn_sched_barrier(0);
    if (pref) { ISS_A(0, kt + 1, nb); ISS_A(2, kt + 1, nb); ISS_B(0, kt + 1, nb); ISS_B(1, kt + 1, nb); }
#pragma unroll
    for (int ni = 0; ni < 4; ++ni) {
      const int r = wcol * 64 + ni * 16 + lr;
#pragma unroll
      for (int ks = 0; ks < 2; ++ks)
        bfr[ni][ks] = *(const bf16x8*)((const char*)&Bl[bufc][0] + r * 128 + ((ks * 64 + lg * 16) ^ rsw));
    }
#pragma unroll
    for (int mq = 0; mq < 2; ++mq) {
      const int r = wrow * 64 + mq * 16 + lr;
#pragma unroll
      for (int ks = 0; ks < 2; ++ks)
        af[mq][ks] = *(const bf16x8*)((const char*)&Al[bufc][0] + r * 128 + ((ks * 64 + lg * 16) ^ rsw));
    }
    __builtin_amdgcn_s_setprio(1);
#pragma unroll
    for (int mq = 0; mq < 2; ++mq)
#pragma unroll
      for (int ni = 0; ni < 4; ++ni)
#pragma unroll
        for (int ks = 0; ks < 2; ++ks)
          acc[mq][ni] = __builtin_amdgcn_mfma_f32_16x16x32_bf16(af[mq][ks], bfr[ni][ks], acc[mq][ni], 0, 0, 0);
    __builtin_amdgcn_s_setprio(0);
    // ---------------- Phase 2: M-half 1
    __builtin_amdgcn_sched_barrier(0);
    if (pref) asm volatile("s_waitcnt vmcnt(4)" ::: "memory");
    else      asm volatile("s_waitcnt vmcnt(0)" ::: "memory");
    __builtin_amdgcn_s_barrier();
    __builtin_amdgcn_sched_barrier(0);
    if (pref) { ISS_B(2, kt + 1, nb); ISS_B(3, kt + 1, nb); ISS_A(1, kt + 1, nb); ISS_A(3, kt + 1, nb); }
#pragma unroll
    for (int mq = 0; mq < 2; ++mq) {
      const int r = wrow * 64 + 32 + mq * 16 + lr;
#pragma unroll
      for (int ks = 0; ks < 2; ++ks)
        af[mq][ks] = *(const bf16x8*)((const char*)&Al[bufc][0] + r * 128 + ((ks * 64 + lg * 16) ^ rsw));
    }
    __builtin_amdgcn_s_setprio(1);
#pragma unroll
    for (int mq = 0; mq < 2; ++mq)
#pragma unroll
      for (int ni = 0; ni < 4; ++ni)
#pragma unroll
        for (int ks = 0; ks < 2; ++ks)
          acc[2 + mq][ni] = __builtin_amdgcn_mfma_f32_16x16x32_bf16(af[mq][ks], bfr[ni][ks], acc[2 + mq][ni], 0, 0, 0);
    __builtin_amdgcn_s_setprio(0);
    bufc ^= 1;
  }
#undef ISS_A
#undef ISS_B
#pragma unroll
  for (int mi = 0; mi < 4; ++mi) {
#pragma unroll
    for (int ni = 0; ni < 4; ++ni) {
      const int cg = col0 + wcol * 64 + ni * 16 + lr;
#pragma unroll
      for (int r = 0; r < 4; ++r) {
        const int rg = row0 + wrow * 64 + mi * 16 + lg * 4 + r;
        epi_store(EPI, (size_t)rg * N + cg, cg, acc[mi][ni][r], bias, resid, scale, outb, outf);
      }
    }
  }
}

// ---------------------------------------------------------------- attention
__launch_bounds__(512, 4)
__global__ void attn_kernel(const short* __restrict__ Qg, const short* __restrict__ Kg,
                            const short* __restrict__ Vtg, short* __restrict__ AO) {
  __shared__ short Kl[2][64 * 64];
  __shared__ short Vl[2][64 * 64];
  __shared__ short Pl[8][32 * 64];
  const int tid = threadIdx.x;
  const int lane = tid & 63, w = tid >> 6;
  const int lg = lane >> 4, lr = lane & 15;

  const int id = blockIdx.x;  // 512 blocks
  const int xcd = id & 7, j = id >> 3;
  const int bh = xcd * 8 + (j & 7);
  const int qblk = j >> 3;
  const int b = bh >> 4, h = bh & 15;
  const int q0 = qblk * 256 + w * 32;

  bf16x8 qf[2][2];
#pragma unroll
  for (int qb = 0; qb < 2; ++qb) {
    const short* qp = Qg + ((size_t)b * 2048 + q0 + qb * 16 + lr) * 1024 + h * 64 + lg * 8;
    qf[qb][0] = *(const bf16x8*)qp;
    qf[qb][1] = *(const bf16x8*)(qp + 32);
  }

  const int srow = lane >> 3;
  const int scb = ((lane & 7) << 4) ^ (srow << 4);
  const char* Ks = (const char*)Kg + ((size_t)b * 2048 + w * 8 + srow) * 2048 + h * 128 + scb;
  const char* Vs = (const char*)Vtg + ((size_t)bh * 64 + w * 8 + srow) * 4096 + scb;
  char* KB[2] = {(char*)&Kl[0][0] + w * 1024, (char*)&Kl[1][0] + w * 1024};
  char* VB[2] = {(char*)&Vl[0][0] + w * 1024, (char*)&Vl[1][0] + w * 1024};

  f32x4 acc[2][4] = {};
  float m_run[2] = {-1e30f, -1e30f};
  float l_run[2] = {0.f, 0.f};
  char* Pw = (char*)&Pl[w][0];
  const int sw = (lr & 7) << 4;

  gload_lds16(Ks, KB[0]);
  gload_lds16(Vs, VB[0]);
  __syncthreads();
  int buf = 0;

  for (int kv0 = 0; kv0 < 2048; kv0 += 64) {
    if (kv0 + 64 < 2048) {
      gload_lds16(Ks + (size_t)(kv0 + 64) * 2048, KB[buf ^ 1]);
      gload_lds16(Vs + (size_t)(kv0 + 64) * 2, VB[buf ^ 1]);
    }
    f32x4 st[4][2];
#pragma unroll
    for (int t = 0; t < 4; ++t) {
      const char* kb = (const char*)&Kl[buf][0] + (t * 16 + lr) * 128;
      const bf16x8 kf0 = *(const bf16x8*)(kb + ((lg * 16) ^ sw));
      const bf16x8 kf1 = *(const bf16x8*)(kb + ((64 + lg * 16) ^ sw));
#pragma unroll
      for (int qb = 0; qb < 2; ++qb) {
        f32x4 z = {};
        z = __builtin_amdgcn_mfma_f32_16x16x32_bf16(kf0, qf[qb][0], z, 0, 0, 0);
        z = __builtin_amdgcn_mfma_f32_16x16x32_bf16(kf1, qf[qb][1], z, 0, 0, 0);
        st[t][qb] = z;
      }
    }
#pragma unroll
    for (int qb = 0; qb < 2; ++qb) {
      float smax = st[0][qb][0];
#pragma unroll
      for (int t = 0; t < 4; ++t)
#pragma unroll
        for (int r = 0; r < 4; ++r) smax = fmaxf(smax, st[t][qb][r]);
      smax = fmaxf(smax, __shfl_xor(smax, 16));
      smax = fmaxf(smax, __shfl_xor(smax, 32));
      float m_use = m_run[qb];
      if (!__all(smax - m_use <= 8.f)) {
        const float mnew = fmaxf(m_use, smax);
        const float alpha = __builtin_amdgcn_exp2f(m_use - mnew);
        m_run[qb] = mnew;
        m_use = mnew;
        l_run[qb] *= alpha;
        float ar[4];
#pragma unroll
        for (int r = 0; r < 4; ++r) ar[r] = __shfl(alpha, lg * 4 + r);
#pragma unroll
        for (int dt = 0; dt < 4; ++dt)
#pragma unroll
          for (int r = 0; r < 4; ++r) acc[qb][dt][r] *= ar[r];
      }
      float rsum = 0.f;
#pragma unroll
      for (int t = 0; t < 4; ++t) {
        bf16x4 pk;
        float ps = 0.f;
#pragma unroll
        for (int r = 0; r < 4; ++r) {
          const float p = __builtin_amdgcn_exp2f(st[t][qb][r] - m_use);
          ps += p;
          pk[r] = (__bf16)p;
        }
        rsum += ps;
        *(bf16x4*)(Pw + (qb * 16 + lr) * 128 + ((t * 32 + lg * 8) ^ sw)) = pk;
      }
      rsum += __shfl_xor(rsum, 16);
      rsum += __shfl_xor(rsum, 32);
      l_run[qb] += rsum;
    }
#pragma unroll
    for (int c = 0; c < 2; ++c) {
      const bf16x8 pf0 = *(const bf16x8*)(Pw + lr * 128 + ((c * 64 + lg * 16) ^ sw));
      const bf16x8 pf1 = *(const bf16x8*)(Pw + (16 + lr) * 128 + ((c * 64 + lg * 16) ^ sw));
#pragma unroll
      for (int dt = 0; dt < 4; ++dt) {
        const bf16x8 vf = *(const bf16x8*)((const char*)&Vl[buf][0] + (dt * 16 + lr) * 128 +
                                           ((c * 64 + lg * 16) ^ sw));
        acc[0][dt] = __builtin_amdgcn_mfma_f32_16x16x32_bf16(pf0, vf, acc[0][dt], 0, 0, 0);
        acc[1][dt] = __builtin_amdgcn_mfma_f32_16x16x32_bf16(pf1, vf, acc[1][dt], 0, 0, 0);
      }
    }
    __syncthreads();
    buf ^= 1;
  }
#pragma unroll
  for (int qb = 0; qb < 2; ++qb) {
    const float linv = 1.f / l_run[qb];
    float lv[4];
#pragma unroll
    for (int r = 0; r < 4; ++r) lv[r] = __shfl(linv, lg * 4 + r);
#pragma unroll
    for (int dt = 0; dt < 4; ++dt)
#pragma unroll
      for (int r = 0; r < 4; ++r)
        AO[((size_t)b * 2048 + q0 + qb * 16 + lg * 4 + r) * 1024 + h * 64 + dt * 16 + lr] =
            f2bf(acc[qb][dt][r] * lv[r]);
  }
}

// ---------------------------------------------------------------- launch
extern "C" void kernel_launch(void* const* d_in, const int* in_sizes, int n_in,
                              void* d_out, int out_size, void* d_ws, size_t ws_size,
                              hipStream_t stream) {
  const float* x   = (const float*)d_in[0];
  const float* ctx = (const float*)d_in[1];
  const float* Wq  = (const float*)d_in[2];
  const float* Wk  = (const float*)d_in[3];
  const float* Wv  = (const float*)d_in[4];
  const float* Wo  = (const float*)d_in[5];
  const float* bo  = (const float*)d_in[6];
  const float* g_q = (const float*)d_in[7];
  const float* b_q = (const float*)d_in[8];
  const float* g_k = (const float*)d_in[9];
  const float* b_k = (const float*)d_in[10];
  const float* g_m = (const float*)d_in[11];
  const float* b_m = (const float*)d_in[12];
  const float* W1  = (const float*)d_in[13];
  const float* b1  = (const float*)d_in[14];
  const float* W2  = (const float*)d_in[15];
  const float* b2  = (const float*)d_in[16];
  float* out = (float*)d_out;

  short* p = (short*)d_ws;
  short* xn  = p; p += (size_t)8192 * 1024;
  short* cn  = p; p += (size_t)8192 * 1024;
  short* Qb  = p; p += (size_t)8192 * 1024;
  short* Kb  = p; p += (size_t)8192 * 1024;
  short* Vb  = p; p += (size_t)8192 * 1024;
  short* Vts = p; p += (size_t)8192 * 1024;
  short* AO  = p; p += (size_t)8192 * 1024;
  short* hn  = p; p += (size_t)8192 * 1024;
  short* hm  = p; p += (size_t)8192 * 4096;
  short* WqT = p; p += (size_t)1024 * 1024;
  short* WkT = p; p += (size_t)1024 * 1024;
  short* WvT = p; p += (size_t)1024 * 1024;
  short* WoT = p; p += (size_t)1024 * 1024;
  short* W1T = p; p += (size_t)1024 * 4096;
  short* W2T = p; p += (size_t)4096 * 1024;
  float* x2  = (float*)p;  // 8192*1024 fp32

  const dim3 tb(32, 8);
  transpose_f32_bf16<<<dim3(32, 32), tb, 0, stream>>>(Wq, WqT, 1024, 1024);
  transpose_f32_bf16<<<dim3(32, 32), tb, 0, stream>>>(Wk, WkT, 1024, 1024);
  transpose_f32_bf16<<<dim3(32, 32), tb, 0, stream>>>(Wv, WvT, 1024, 1024);
  transpose_f32_bf16<<<dim3(32, 32), tb, 0, stream>>>(Wo, WoT, 1024, 1024);
  transpose_f32_bf16<<<dim3(128, 32), tb, 0, stream>>>(W1, W1T, 1024, 4096);
  transpose_f32_bf16<<<dim3(32, 128), tb, 0, stream>>>(W2, W2T, 4096, 1024);

  ln_kernel<<<8192, 256, 0, stream>>>(x, g_q, b_q, xn);
  ln_kernel<<<8192, 256, 0, stream>>>(ctx, g_k, b_k, cn);

  const float qscale = 0.125f * 1.44269504088896340736f;  // 1/sqrt(64) * log2(e)
  // N=1024 GEMMs: gemm128, grid 8x64 = 512 blocks
  gemm128<EPI_Q><<<512, 256, 0, stream>>>(xn, WqT, 1024, 1024, 8, nullptr, nullptr, qscale, Qb, nullptr);
  gemm128<EPI_PLAIN><<<512, 256, 0, stream>>>(cn, WkT, 1024, 1024, 8, nullptr, nullptr, 0.f, Kb, nullptr);
  gemm128<EPI_PLAIN><<<512, 256, 0, stream>>>(cn, WvT, 1024, 1024, 8, nullptr, nullptr, 0.f, Vb, nullptr);

  transpose_v<<<dim3(64, 2, 64), tb, 0, stream>>>(Vb, Vts);

  attn_kernel<<<512, 512, 0, stream>>>(Qb, Kb, Vts, AO);

  gemm128<EPI_BIAS_RESID_F32><<<512, 256, 0, stream>>>(AO, WoT, 1024, 1024, 8, bo, x, 0.f, nullptr, x2);

  ln_kernel<<<8192, 256, 0, stream>>>(x2, g_m, b_m, hn);

  // W1: N=4096 -> gemm256, grid 16x32 = 512 blocks
  gemm256<EPI_BIAS_SILU><<<512, 512, 0, stream>>>(hn, W1T, 4096, 1024, 16, b1, nullptr, 0.f, hm, nullptr);
  // W2: N=1024, K=4096 -> gemm128
  gemm128<EPI_BIAS_RESID_F32><<<512, 256, 0, stream>>>(hm, W2T, 1024, 4096, 8, b2, x2, 0.f, nullptr, out);
}

// Round 4
// 491.520 us; speedup vs baseline: 1.0093x; 1.0093x over previous
//
#include <hip/hip_runtime.h>
#include <hip/hip_bf16.h>

// CrossAttentionLayer on MI355X (gfx950), round 4.
// Round-4 change: GEMMs rebuilt with fine-grained phase schedules + chunk
// ledger (derived from the m201 8-phase template):
//   gemm8p: 256x256, BK=64, 8 waves (2Mx4N), 4 phases/K-tile (C-quadrants),
//           16 MFMA/phase, stages: P1->A1,A3(t+1) P2->A0,A2(t+1)
//           P3,P4->B0..3(t+2), one vmcnt(4) per K-tile.   -> W1
//   gemmW:  256x128, BK=64, 8 waves (4Mx2N), 2 phases/K-tile, 16 MFMA/phase,
//           stages: P1->A0,A1,A2(t+1) P2->A3(t+1),B0,B1(t+2), vmcnt(2)/tile.
//           grid=256 blocks (1/CU).                        -> Q,K,V,Wo,W2
// Attention/LN/transposes unchanged (round 2).

typedef __bf16 bf16x8 __attribute__((ext_vector_type(8)));
typedef __bf16 bf16x4 __attribute__((ext_vector_type(4)));
typedef float f32x4 __attribute__((ext_vector_type(4)));

#define DEV static __device__ __forceinline__

DEV short f2bf(float x) {  // RNE float->bf16
  union { float f; unsigned u; } c; c.f = x;
  unsigned r = c.u + 0x7fffu + ((c.u >> 16) & 1u);
  return (short)(r >> 16);
}

DEV void gload_lds16(const void* g, void* l) {
  __builtin_amdgcn_global_load_lds((__attribute__((address_space(1))) void*)g,
                                   (__attribute__((address_space(3))) void*)l, 16, 0, 0);
}

DEV void phase_fence() {
  __builtin_amdgcn_s_barrier();
  __builtin_amdgcn_sched_barrier(0);
}

// ---------------------------------------------------------------- transpose
__launch_bounds__(256, 4)
__global__ void transpose_f32_bf16(const float* __restrict__ in, short* __restrict__ outT,
                                   int R, int C) {
  __shared__ float t[32][33];
  const int c0 = blockIdx.x * 32, r0 = blockIdx.y * 32;
  const int tx = threadIdx.x, ty = threadIdx.y;
#pragma unroll
  for (int i = 0; i < 4; ++i)
    t[ty + 8 * i][tx] = in[(size_t)(r0 + ty + 8 * i) * C + (c0 + tx)];
  __syncthreads();
#pragma unroll
  for (int i = 0; i < 4; ++i)
    outT[(size_t)(c0 + ty + 8 * i) * R + (r0 + tx)] = f2bf(t[tx][ty + 8 * i]);
}

// V [B*2048][1024](bf16) -> Vt [bh][64][2048](bf16)
__launch_bounds__(256, 4)
__global__ void transpose_v(const short* __restrict__ V, short* __restrict__ Vt) {
  __shared__ short t[32][33];
  const int m0 = blockIdx.x * 32;
  const int d0 = blockIdx.y * 32;
  const int bh = blockIdx.z;
  const int b = bh >> 4, h = bh & 15;
  const int tx = threadIdx.x, ty = threadIdx.y;
#pragma unroll
  for (int i = 0; i < 4; ++i)
    t[ty + 8 * i][tx] = V[((size_t)b * 2048 + m0 + ty + 8 * i) * 1024 + h * 64 + d0 + tx];
  __syncthreads();
#pragma unroll
  for (int i = 0; i < 4; ++i)
    Vt[((size_t)bh * 64 + d0 + ty + 8 * i) * 2048 + (m0 + tx)] = t[tx][ty + 8 * i];
}

// ---------------------------------------------------------------- layernorm
__launch_bounds__(256, 4)
__global__ void ln_kernel(const float* __restrict__ in, const float* __restrict__ g,
                          const float* __restrict__ b, short* __restrict__ out) {
  const int row = blockIdx.x;
  const int tid = threadIdx.x;
  const float4 v = ((const float4*)(in + (size_t)row * 1024))[tid];
  float s = v.x + v.y + v.z + v.w;
  float s2 = v.x * v.x + v.y * v.y + v.z * v.z + v.w * v.w;
#pragma unroll
  for (int off = 1; off < 64; off <<= 1) {
    s += __shfl_xor(s, off);
    s2 += __shfl_xor(s2, off);
  }
  __shared__ float ps[4], pq[4];
  const int w = tid >> 6, lane = tid & 63;
  if (lane == 0) { ps[w] = s; pq[w] = s2; }
  __syncthreads();
  s = ps[0] + ps[1] + ps[2] + ps[3];
  s2 = pq[0] + pq[1] + pq[2] + pq[3];
  const float mu = s * (1.f / 1024.f);
  const float rs = rsqrtf(s2 * (1.f / 1024.f) - mu * mu + 1e-5f);
  const float4 gg = ((const float4*)g)[tid];
  const float4 bb = ((const float4*)b)[tid];
  short4 o4;
  o4.x = f2bf((v.x - mu) * rs * gg.x + bb.x);
  o4.y = f2bf((v.y - mu) * rs * gg.y + bb.y);
  o4.z = f2bf((v.z - mu) * rs * gg.z + bb.z);
  o4.w = f2bf((v.w - mu) * rs * gg.w + bb.w);
  ((short4*)(out + (size_t)row * 1024))[tid] = o4;
}

// ---------------------------------------------------------------- GEMM epi
enum { EPI_Q = 0, EPI_PLAIN = 1, EPI_BIAS_RESID_F32 = 2, EPI_BIAS_SILU = 3 };

DEV void epi_store(int EPI, size_t idx, int cg, float v, const float* bias,
                   const float* resid, float scale, short* outb, float* outf) {
  if (EPI == EPI_Q) {
    outb[idx] = f2bf(v * scale);
  } else if (EPI == EPI_PLAIN) {
    outb[idx] = f2bf(v);
  } else if (EPI == EPI_BIAS_RESID_F32) {
    outf[idx] = v + bias[cg] + resid[idx];
  } else {
    const float u = v + bias[cg];
    outb[idx] = f2bf(u / (1.f + __expf(-u)));
  }
}

// ---------------------------------------------------------------- gemm8p
// BM=BN=256, BK=64, 512 thr. Waves 2Mx4N: per-wave 128x64 out.
// Chunks: A0..A3 / B0..B3 = 64 rows each, one global_load_lds instr per chunk.
// Phase reads (per wave): P1: A-qm0(8)+B-qn0(4); P2: B-qn1(4); P3: A-qm1(8); P4: 0.
// Region liveness: A0,A2 dead after P1; B dead after P2; A1,A3 dead after P3.
template <int EPI>
__launch_bounds__(512, 2)
__global__ void gemm8p(const short* __restrict__ A, const short* __restrict__ Bt,
                       int N, int K, int nbx, const float* __restrict__ bias,
                       const float* __restrict__ resid, float scale,
                       short* __restrict__ outb, float* __restrict__ outf) {
  __shared__ short Al[2][256 * 64];
  __shared__ short Bl[2][256 * 64];
  const int tid = threadIdx.x;
  const int lane = tid & 63, w = tid >> 6;
  const int wr = w >> 2, wc = w & 3;
  const int lg = lane >> 4, lr = lane & 15;

  const int nwg = gridDim.x;
  const int id = blockIdx.x;
  const int swz = (id & 7) * (nwg >> 3) + (id >> 3);  // nwg % 8 == 0
  const int bx = swz % nbx, by = swz / nbx;
  const int row0 = by * 256, col0 = bx * 256;

  const size_t AROW = (size_t)K * 2;
  const int scb = ((tid & 7) << 4) ^ (((tid >> 3) & 7) << 4);
  const char* Asrc = (const char*)A + (size_t)(row0 + (tid >> 3)) * AROW + scb;
  const char* Bsrc = (const char*)Bt + (size_t)(col0 + (tid >> 3)) * AROW + scb;
  const int wdst = w * 1024;
  const int rsw = (lr & 7) << 4;
  const int KT = K >> 6;

#define ISS8_A(i, kt, b) gload_lds16(Asrc + (size_t)((i) * 64) * AROW + (size_t)(kt) * 128, \
                                     (char*)&Al[b][0] + (i) * 8192 + wdst)
#define ISS8_B(i, kt, b) gload_lds16(Bsrc + (size_t)((i) * 64) * AROW + (size_t)(kt) * 128, \
                                     (char*)&Bl[b][0] + (i) * 8192 + wdst)
#define RD_A(qm, mq, ks) *(const bf16x8*)((const char*)&Al[c][0] + \
    (wr * 128 + (qm) * 64 + (mq) * 16 + lr) * 128 + (((ks) * 64 + lg * 16) ^ rsw))
#define RD_B(qn, ni, ks) *(const bf16x8*)((const char*)&Bl[c][0] + \
    (wc * 64 + (qn) * 32 + (ni) * 16 + lr) * 128 + (((ks) * 64 + lg * 16) ^ rsw))

  // prologue (stream order matches steady-state ledger):
  ISS8_B(0, 0, 0); ISS8_B(1, 0, 0); ISS8_B(2, 0, 0); ISS8_B(3, 0, 0);
  ISS8_A(1, 0, 0); ISS8_A(3, 0, 0);
  ISS8_A(0, 0, 0); ISS8_A(2, 0, 0);
  ISS8_B(0, 1, 1); ISS8_B(1, 1, 1); ISS8_B(2, 1, 1); ISS8_B(3, 1, 1);

  f32x4 acc[8][4] = {};
  bf16x8 af[4][2], bq[2][2][2];

  for (int t = 0; t < KT; ++t) {
    const int c = t & 1, n1 = c ^ 1;
    // ---- P1 (qm=0, qn=0)
    if (t == KT - 1) asm volatile("s_waitcnt vmcnt(0)" ::: "memory");
    else             asm volatile("s_waitcnt vmcnt(4)" ::: "memory");
    phase_fence();
    if (t + 1 < KT) { ISS8_A(1, t + 1, n1); ISS8_A(3, t + 1, n1); }
#pragma unroll
    for (int mq = 0; mq < 4; ++mq) { af[mq][0] = RD_A(0, mq, 0); af[mq][1] = RD_A(0, mq, 1); }
#pragma unroll
    for (int ni = 0; ni < 2; ++ni) { bq[0][ni][0] = RD_B(0, ni, 0); bq[0][ni][1] = RD_B(0, ni, 1); }
    __builtin_amdgcn_s_setprio(1);
#pragma unroll
    for (int mq = 0; mq < 4; ++mq)
#pragma unroll
      for (int ni = 0; ni < 2; ++ni)
#pragma unroll
        for (int ks = 0; ks < 2; ++ks)
          acc[mq][ni] = __builtin_amdgcn_mfma_f32_16x16x32_bf16(af[mq][ks], bq[0][ni][ks], acc[mq][ni], 0, 0, 0);
    __builtin_amdgcn_s_setprio(0);
    // ---- P2 (qm=0, qn=1)
    phase_fence();
    if (t + 1 < KT) { ISS8_A(0, t + 1, n1); ISS8_A(2, t + 1, n1); }
#pragma unroll
    for (int ni = 0; ni < 2; ++ni) { bq[1][ni][0] = RD_B(1, ni, 0); bq[1][ni][1] = RD_B(1, ni, 1); }
    __builtin_amdgcn_s_setprio(1);
#pragma unroll
    for (int mq = 0; mq < 4; ++mq)
#pragma unroll
      for (int ni = 0; ni < 2; ++ni)
#pragma unroll
        for (int ks = 0; ks < 2; ++ks)
          acc[mq][2 + ni] = __builtin_amdgcn_mfma_f32_16x16x32_bf16(af[mq][ks], bq[1][ni][ks], acc[mq][2 + ni], 0, 0, 0);
    __builtin_amdgcn_s_setprio(0);
    // ---- P3 (qm=1, qn=0)
    phase_fence();
    if (t + 2 < KT) { ISS8_B(0, t + 2, c); ISS8_B(1, t + 2, c); }
#pragma unroll
    for (int mq = 0; mq < 4; ++mq) { af[mq][0] = RD_A(1, mq, 0); af[mq][1] = RD_A(1, mq, 1); }
    __builtin_amdgcn_s_setprio(1);
#pragma unroll
    for (int mq = 0; mq < 4; ++mq)
#pragma unroll
      for (int ni = 0; ni < 2; ++ni)
#pragma unroll
        for (int ks = 0; ks < 2; ++ks)
          acc[4 + mq][ni] = __builtin_amdgcn_mfma_f32_16x16x32_bf16(af[mq][ks], bq[0][ni][ks], acc[4 + mq][ni], 0, 0, 0);
    __builtin_amdgcn_s_setprio(0);
    // ---- P4 (qm=1, qn=1)
    phase_fence();
    if (t + 2 < KT) { ISS8_B(2, t + 2, c); ISS8_B(3, t + 2, c); }
    __builtin_amdgcn_s_setprio(1);
#pragma unroll
    for (int mq = 0; mq < 4; ++mq)
#pragma unroll
      for (int ni = 0; ni < 2; ++ni)
#pragma unroll
        for (int ks = 0; ks < 2; ++ks)
          acc[4 + mq][2 + ni] = __builtin_amdgcn_mfma_f32_16x16x32_bf16(af[mq][ks], bq[1][ni][ks], acc[4 + mq][2 + ni], 0, 0, 0);
    __builtin_amdgcn_s_setprio(0);
  }
#undef ISS8_A
#undef ISS8_B
#undef RD_A
#undef RD_B
#pragma unroll
  for (int mi = 0; mi < 8; ++mi) {
#pragma unroll
    for (int nj = 0; nj < 4; ++nj) {
      const int cg = col0 + wc * 64 + (nj >> 1) * 32 + (nj & 1) * 16 + lr;
#pragma unroll
      for (int r = 0; r < 4; ++r) {
        const int rg = row0 + wr * 128 + (mi >> 2) * 64 + (mi & 3) * 16 + lg * 4 + r;
        epi_store(EPI, (size_t)rg * N + cg, cg, acc[mi][nj][r], bias, resid, scale, outb, outf);
      }
    }
  }
}

// ---------------------------------------------------------------- gemmW
// BM=256, BN=128, BK=64, 512 thr. Waves 4Mx2N: per-wave 64x64 out.
// Chunks: A0..A3 (64 rows), B0,B1 (64 rows). 2 phases/K-tile (M-halves).
// Phase reads: P1: A mq0,1 (4) + all B (8); P2: A mq2,3 (4).
// Liveness: A chunks dead after P2; B chunks dead after P1.
template <int EPI>
__launch_bounds__(512, 2)
__global__ void gemmW(const short* __restrict__ A, const short* __restrict__ Bt,
                      int N, int K, int nbx, const float* __restrict__ bias,
                      const float* __restrict__ resid, float scale,
                      short* __restrict__ outb, float* __restrict__ outf) {
  __shared__ short Al[2][256 * 64];
  __shared__ short Bl[2][128 * 64];
  const int tid = threadIdx.x;
  const int lane = tid & 63, w = tid >> 6;
  const int wr = w >> 1, wc = w & 1;
  const int lg = lane >> 4, lr = lane & 15;

  const int nwg = gridDim.x;
  const int id = blockIdx.x;
  const int swz = (id & 7) * (nwg >> 3) + (id >> 3);  // nwg % 8 == 0
  const int bx = swz % nbx, by = swz / nbx;
  const int row0 = by * 256, col0 = bx * 128;

  const size_t AROW = (size_t)K * 2;
  const int scb = ((tid & 7) << 4) ^ (((tid >> 3) & 7) << 4);
  const char* Asrc = (const char*)A + (size_t)(row0 + (tid >> 3)) * AROW + scb;
  const char* Bsrc = (const char*)Bt + (size_t)(col0 + (tid >> 3)) * AROW + scb;
  const int wdst = w * 1024;
  const int rsw = (lr & 7) << 4;
  const int KT = K >> 6;

#define ISSW_A(i, kt, b) gload_lds16(Asrc + (size_t)((i) * 64) * AROW + (size_t)(kt) * 128, \
                                     (char*)&Al[b][0] + (i) * 8192 + wdst)
#define ISSW_B(i, kt, b) gload_lds16(Bsrc + (size_t)((i) * 64) * AROW + (size_t)(kt) * 128, \
                                     (char*)&Bl[b][0] + (i) * 8192 + wdst)
#define RDW_A(mq, ks) *(const bf16x8*)((const char*)&Al[c][0] + \
    (wr * 64 + (mq) * 16 + lr) * 128 + (((ks) * 64 + lg * 16) ^ rsw))
#define RDW_B(ni, ks) *(const bf16x8*)((const char*)&Bl[c][0] + \
    (wc * 64 + (ni) * 16 + lr) * 128 + (((ks) * 64 + lg * 16) ^ rsw))

  // prologue in ledger stream order
  ISSW_B(0, 0, 0); ISSW_B(1, 0, 0);
  ISSW_A(0, 0, 0); ISSW_A(1, 0, 0); ISSW_A(2, 0, 0);
  ISSW_A(3, 0, 0);
  ISSW_B(0, 1, 1); ISSW_B(1, 1, 1);

  f32x4 acc[4][4] = {};
  bf16x8 af[2][2], bq[4][2];

  for (int t = 0; t < KT; ++t) {
    const int c = t & 1, n1 = c ^ 1;
    // ---- P1 (mq 0,1)
    if (t == KT - 1) asm volatile("s_waitcnt vmcnt(0)" ::: "memory");
    else             asm volatile("s_waitcnt vmcnt(2)" ::: "memory");
    phase_fence();
    if (t + 1 < KT) { ISSW_A(0, t + 1, n1); ISSW_A(1, t + 1, n1); ISSW_A(2, t + 1, n1); }
#pragma unroll
    for (int mq = 0; mq < 2; ++mq) { af[mq][0] = RDW_A(mq, 0); af[mq][1] = RDW_A(mq, 1); }
#pragma unroll
    for (int ni = 0; ni < 4; ++ni) { bq[ni][0] = RDW_B(ni, 0); bq[ni][1] = RDW_B(ni, 1); }
    __builtin_amdgcn_s_setprio(1);
#pragma unroll
    for (int mq = 0; mq < 2; ++mq)
#pragma unroll
      for (int ni = 0; ni < 4; ++ni)
#pragma unroll
        for (int ks = 0; ks < 2; ++ks)
          acc[mq][ni] = __builtin_amdgcn_mfma_f32_16x16x32_bf16(af[mq][ks], bq[ni][ks], acc[mq][ni], 0, 0, 0);
    __builtin_amdgcn_s_setprio(0);
    // ---- P2 (mq 2,3)
    phase_fence();
    if (t + 1 < KT) ISSW_A(3, t + 1, n1);
    if (t + 2 < KT) { ISSW_B(0, t + 2, c); ISSW_B(1, t + 2, c); }
#pragma unroll
    for (int mq = 0; mq < 2; ++mq) { af[mq][0] = RDW_A(2 + mq, 0); af[mq][1] = RDW_A(2 + mq, 1); }
    __builtin_amdgcn_s_setprio(1);
#pragma unroll
    for (int mq = 0; mq < 2; ++mq)
#pragma unroll
      for (int ni = 0; ni < 4; ++ni)
#pragma unroll
        for (int ks = 0; ks < 2; ++ks)
          acc[2 + mq][ni] = __builtin_amdgcn_mfma_f32_16x16x32_bf16(af[mq][ks], bq[ni][ks], acc[2 + mq][ni], 0, 0, 0);
    __builtin_amdgcn_s_setprio(0);
  }
#undef ISSW_A
#undef ISSW_B
#undef RDW_A
#undef RDW_B
#pragma unroll
  for (int mi = 0; mi < 4; ++mi) {
#pragma unroll
    for (int ni = 0; ni < 4; ++ni) {
      const int cg = col0 + wc * 64 + ni * 16 + lr;
#pragma unroll
      for (int r = 0; r < 4; ++r) {
        const int rg = row0 + wr * 64 + mi * 16 + lg * 4 + r;
        epi_store(EPI, (size_t)rg * N + cg, cg, acc[mi][ni][r], bias, resid, scale, outb, outf);
      }
    }
  }
}

// ---------------------------------------------------------------- attention
__launch_bounds__(512, 4)
__global__ void attn_kernel(const short* __restrict__ Qg, const short* __restrict__ Kg,
                            const short* __restrict__ Vtg, short* __restrict__ AO) {
  __shared__ short Kl[2][64 * 64];
  __shared__ short Vl[2][64 * 64];
  __shared__ short Pl[8][32 * 64];
  const int tid = threadIdx.x;
  const int lane = tid & 63, w = tid >> 6;
  const int lg = lane >> 4, lr = lane & 15;

  const int id = blockIdx.x;  // 512 blocks
  const int xcd = id & 7, j = id >> 3;
  const int bh = xcd * 8 + (j & 7);
  const int qblk = j >> 3;
  const int b = bh >> 4, h = bh & 15;
  const int q0 = qblk * 256 + w * 32;

  bf16x8 qf[2][2];
#pragma unroll
  for (int qb = 0; qb < 2; ++qb) {
    const short* qp = Qg + ((size_t)b * 2048 + q0 + qb * 16 + lr) * 1024 + h * 64 + lg * 8;
    qf[qb][0] = *(const bf16x8*)qp;
    qf[qb][1] = *(const bf16x8*)(qp + 32);
  }

  const int srow = lane >> 3;
  const int scb = ((lane & 7) << 4) ^ (srow << 4);
  const char* Ks = (const char*)Kg + ((size_t)b * 2048 + w * 8 + srow) * 2048 + h * 128 + scb;
  const char* Vs = (const char*)Vtg + ((size_t)bh * 64 + w * 8 + srow) * 4096 + scb;
  char* KB[2] = {(char*)&Kl[0][0] + w * 1024, (char*)&Kl[1][0] + w * 1024};
  char* VB[2] = {(char*)&Vl[0][0] + w * 1024, (char*)&Vl[1][0] + w * 1024};

  f32x4 acc[2][4] = {};
  float m_run[2] = {-1e30f, -1e30f};
  float l_run[2] = {0.f, 0.f};
  char* Pw = (char*)&Pl[w][0];
  const int sw = (lr & 7) << 4;

  gload_lds16(Ks, KB[0]);
  gload_lds16(Vs, VB[0]);
  __syncthreads();
  int buf = 0;

  for (int kv0 = 0; kv0 < 2048; kv0 += 64) {
    if (kv0 + 64 < 2048) {
      gload_lds16(Ks + (size_t)(kv0 + 64) * 2048, KB[buf ^ 1]);
      gload_lds16(Vs + (size_t)(kv0 + 64) * 2, VB[buf ^ 1]);
    }
    f32x4 st[4][2];
#pragma unroll
    for (int t = 0; t < 4; ++t) {
      const char* kb = (const char*)&Kl[buf][0] + (t * 16 + lr) * 128;
      const bf16x8 kf0 = *(const bf16x8*)(kb + ((lg * 16) ^ sw));
      const bf16x8 kf1 = *(const bf16x8*)(kb + ((64 + lg * 16) ^ sw));
#pragma unroll
      for (int qb = 0; qb < 2; ++qb) {
        f32x4 z = {};
        z = __builtin_amdgcn_mfma_f32_16x16x32_bf16(kf0, qf[qb][0], z, 0, 0, 0);
        z = __builtin_amdgcn_mfma_f32_16x16x32_bf16(kf1, qf[qb][1], z, 0, 0, 0);
        st[t][qb] = z;
      }
    }
#pragma unroll
    for (int qb = 0; qb < 2; ++qb) {
      float smax = st[0][qb][0];
#pragma unroll
      for (int t = 0; t < 4; ++t)
#pragma unroll
        for (int r = 0; r < 4; ++r) smax = fmaxf(smax, st[t][qb][r]);
      smax = fmaxf(smax, __shfl_xor(smax, 16));
      smax = fmaxf(smax, __shfl_xor(smax, 32));
      float m_use = m_run[qb];
      if (!__all(smax - m_use <= 8.f)) {
        const float mnew = fmaxf(m_use, smax);
        const float alpha = __builtin_amdgcn_exp2f(m_use - mnew);
        m_run[qb] = mnew;
        m_use = mnew;
        l_run[qb] *= alpha;
        float ar[4];
#pragma unroll
        for (int r = 0; r < 4; ++r) ar[r] = __shfl(alpha, lg * 4 + r);
#pragma unroll
        for (int dt = 0; dt < 4; ++dt)
#pragma unroll
          for (int r = 0; r < 4; ++r) acc[qb][dt][r] *= ar[r];
      }
      float rsum = 0.f;
#pragma unroll
      for (int t = 0; t < 4; ++t) {
        bf16x4 pk;
        float ps = 0.f;
#pragma unroll
        for (int r = 0; r < 4; ++r) {
          const float p = __builtin_amdgcn_exp2f(st[t][qb][r] - m_use);
          ps += p;
          pk[r] = (__bf16)p;
        }
        rsum += ps;
        *(bf16x4*)(Pw + (qb * 16 + lr) * 128 + ((t * 32 + lg * 8) ^ sw)) = pk;
      }
      rsum += __shfl_xor(rsum, 16);
      rsum += __shfl_xor(rsum, 32);
      l_run[qb] += rsum;
    }
#pragma unroll
    for (int c = 0; c < 2; ++c) {
      const bf16x8 pf0 = *(const bf16x8*)(Pw + lr * 128 + ((c * 64 + lg * 16) ^ sw));
      const bf16x8 pf1 = *(const bf16x8*)(Pw + (16 + lr) * 128 + ((c * 64 + lg * 16) ^ sw));
#pragma unroll
      for (int dt = 0; dt < 4; ++dt) {
        const bf16x8 vf = *(const bf16x8*)((const char*)&Vl[buf][0] + (dt * 16 + lr) * 128 +
                                           ((c * 64 + lg * 16) ^ sw));
        acc[0][dt] = __builtin_amdgcn_mfma_f32_16x16x32_bf16(pf0, vf, acc[0][dt], 0, 0, 0);
        acc[1][dt] = __builtin_amdgcn_mfma_f32_16x16x32_bf16(pf1, vf, acc[1][dt], 0, 0, 0);
      }
    }
    __syncthreads();
    buf ^= 1;
  }
#pragma unroll
  for (int qb = 0; qb < 2; ++qb) {
    const float linv = 1.f / l_run[qb];
    float lv[4];
#pragma unroll
    for (int r = 0; r < 4; ++r) lv[r] = __shfl(linv, lg * 4 + r);
#pragma unroll
    for (int dt = 0; dt < 4; ++dt)
#pragma unroll
      for (int r = 0; r < 4; ++r)
        AO[((size_t)b * 2048 + q0 + qb * 16 + lg * 4 + r) * 1024 + h * 64 + dt * 16 + lr] =
            f2bf(acc[qb][dt][r] * lv[r]);
  }
}

// ---------------------------------------------------------------- launch
extern "C" void kernel_launch(void* const* d_in, const int* in_sizes, int n_in,
                              void* d_out, int out_size, void* d_ws, size_t ws_size,
                              hipStream_t stream) {
  const float* x   = (const float*)d_in[0];
  const float* ctx = (const float*)d_in[1];
  const float* Wq  = (const float*)d_in[2];
  const float* Wk  = (const float*)d_in[3];
  const float* Wv  = (const float*)d_in[4];
  const float* Wo  = (const float*)d_in[5];
  const float* bo  = (const float*)d_in[6];
  const float* g_q = (const float*)d_in[7];
  const float* b_q = (const float*)d_in[8];
  const float* g_k = (const float*)d_in[9];
  const float* b_k = (const float*)d_in[10];
  const float* g_m = (const float*)d_in[11];
  const float* b_m = (const float*)d_in[12];
  const float* W1  = (const float*)d_in[13];
  const float* b1  = (const float*)d_in[14];
  const float* W2  = (const float*)d_in[15];
  const float* b2  = (const float*)d_in[16];
  float* out = (float*)d_out;

  short* p = (short*)d_ws;
  short* xn  = p; p += (size_t)8192 * 1024;
  short* cn  = p; p += (size_t)8192 * 1024;
  short* Qb  = p; p += (size_t)8192 * 1024;
  short* Kb  = p; p += (size_t)8192 * 1024;
  short* Vb  = p; p += (size_t)8192 * 1024;
  short* Vts = p; p += (size_t)8192 * 1024;
  short* AO  = p; p += (size_t)8192 * 1024;
  short* hn  = p; p += (size_t)8192 * 1024;
  short* hm  = p; p += (size_t)8192 * 4096;
  short* WqT = p; p += (size_t)1024 * 1024;
  short* WkT = p; p += (size_t)1024 * 1024;
  short* WvT = p; p += (size_t)1024 * 1024;
  short* WoT = p; p += (size_t)1024 * 1024;
  short* W1T = p; p += (size_t)1024 * 4096;
  short* W2T = p; p += (size_t)4096 * 1024;
  float* x2  = (float*)p;  // 8192*1024 fp32

  const dim3 tb(32, 8);
  transpose_f32_bf16<<<dim3(32, 32), tb, 0, stream>>>(Wq, WqT, 1024, 1024);
  transpose_f32_bf16<<<dim3(32, 32), tb, 0, stream>>>(Wk, WkT, 1024, 1024);
  transpose_f32_bf16<<<dim3(32, 32), tb, 0, stream>>>(Wv, WvT, 1024, 1024);
  transpose_f32_bf16<<<dim3(32, 32), tb, 0, stream>>>(Wo, WoT, 1024, 1024);
  transpose_f32_bf16<<<dim3(128, 32), tb, 0, stream>>>(W1, W1T, 1024, 4096);
  transpose_f32_bf16<<<dim3(32, 128), tb, 0, stream>>>(W2, W2T, 4096, 1024);

  ln_kernel<<<8192, 256, 0, stream>>>(x, g_q, b_q, xn);
  ln_kernel<<<8192, 256, 0, stream>>>(ctx, g_k, b_k, cn);

  const float qscale = 0.125f * 1.44269504088896340736f;  // 1/sqrt(64) * log2(e)
  // N=1024 GEMMs: gemmW (256x128), grid 32x8 = 256 blocks (1/CU)
  gemmW<EPI_Q><<<256, 512, 0, stream>>>(xn, WqT, 1024, 1024, 8, nullptr, nullptr, qscale, Qb, nullptr);
  gemmW<EPI_PLAIN><<<256, 512, 0, stream>>>(cn, WkT, 1024, 1024, 8, nullptr, nullptr, 0.f, Kb, nullptr);
  gemmW<EPI_PLAIN><<<256, 512, 0, stream>>>(cn, WvT, 1024, 1024, 8, nullptr, nullptr, 0.f, Vb, nullptr);

  transpose_v<<<dim3(64, 2, 64), tb, 0, stream>>>(Vb, Vts);

  attn_kernel<<<512, 512, 0, stream>>>(Qb, Kb, Vts, AO);

  gemmW<EPI_BIAS_RESID_F32><<<256, 512, 0, stream>>>(AO, WoT, 1024, 1024, 8, bo, x, 0.f, nullptr, x2);

  ln_kernel<<<8192, 256, 0, stream>>>(x2, g_m, b_m, hn);

  // W1: N=4096 -> gemm8p (256x256), grid 32x16 = 512 blocks
  gemm8p<EPI_BIAS_SILU><<<512, 512, 0, stream>>>(hn, W1T, 4096, 1024, 16, b1, nullptr, 0.f, hm, nullptr);
  // W2: N=1024, K=4096 -> gemmW
  gemmW<EPI_BIAS_RESID_F32><<<256, 512, 0, stream>>>(hm, W2T, 1024, 4096, 8, b2, x2, 0.f, nullptr, out);
}

// Round 7
// 432.506 us; speedup vs baseline: 1.1470x; 1.1364x over previous
//
#include <hip/hip_runtime.h>
#include <hip/hip_bf16.h>

// CrossAttentionLayer on MI355X (gfx950), round 7.
// Round-7 change: fix the deterministic accumulator-indexing bug in the
// 8-phase GEMM core (m225 lesson): P5-P8 were writing acc[8..15] (OOB, K-tile
// indexed). K-tiles must ACCUMULATE into the same C-quadrants: P5-P8 now use
// MFMA_Q(0,0)/(0,1)/(1,0)/(1,1) reading LDS buf 1. Schedule itself unchanged
// from round 6: per phase [vmcnt@P1/P5] -> entry s_barrier -> ds_reads +
// stage-issues -> lgkmcnt(0)+sched_barrier -> 16 MFMA (setprio).
// Stages: P3:B(t+2) P4:A(t+2) P7:B(t+3) P8:A(t+3); vmcnt(8) at P1/P5.
// KV fused (N=2048); W2 split-K=2 + fused reduce. Attention/LN as round 2.

typedef __bf16 bf16x8 __attribute__((ext_vector_type(8)));
typedef __bf16 bf16x4 __attribute__((ext_vector_type(4)));
typedef float f32x4 __attribute__((ext_vector_type(4)));

#define DEV static __device__ __forceinline__

DEV short f2bf(float x) {  // RNE float->bf16
  union { float f; unsigned u; } c; c.f = x;
  unsigned r = c.u + 0x7fffu + ((c.u >> 16) & 1u);
  return (short)(r >> 16);
}

DEV void gload_lds16(const void* g, void* l) {
  __builtin_amdgcn_global_load_lds((__attribute__((address_space(1))) void*)g,
                                   (__attribute__((address_space(3))) void*)l, 16, 0, 0);
}

// ---------------------------------------------------------------- transpose
__launch_bounds__(256, 4)
__global__ void transpose_f32_bf16(const float* __restrict__ in, short* __restrict__ outT,
                                   int R, int C) {
  __shared__ float t[32][33];
  const int c0 = blockIdx.x * 32, r0 = blockIdx.y * 32;
  const int tx = threadIdx.x, ty = threadIdx.y;
#pragma unroll
  for (int i = 0; i < 4; ++i)
    t[ty + 8 * i][tx] = in[(size_t)(r0 + ty + 8 * i) * C + (c0 + tx)];
  __syncthreads();
#pragma unroll
  for (int i = 0; i < 4; ++i)
    outT[(size_t)(c0 + ty + 8 * i) * R + (r0 + tx)] = f2bf(t[tx][ty + 8 * i]);
}

// V part of KVb [B*2048][2048](bf16, V at cols 1024..2047) -> Vt [bh][64][2048]
__launch_bounds__(256, 4)
__global__ void transpose_v(const short* __restrict__ KV, short* __restrict__ Vt) {
  __shared__ short t[32][33];
  const int m0 = blockIdx.x * 32;
  const int d0 = blockIdx.y * 32;
  const int bh = blockIdx.z;
  const int b = bh >> 4, h = bh & 15;
  const int tx = threadIdx.x, ty = threadIdx.y;
#pragma unroll
  for (int i = 0; i < 4; ++i)
    t[ty + 8 * i][tx] = KV[((size_t)b * 2048 + m0 + ty + 8 * i) * 2048 + 1024 + h * 64 + d0 + tx];
  __syncthreads();
#pragma unroll
  for (int i = 0; i < 4; ++i)
    Vt[((size_t)bh * 64 + d0 + ty + 8 * i) * 2048 + (m0 + tx)] = t[tx][ty + 8 * i];
}

// ---------------------------------------------------------------- layernorm
__launch_bounds__(256, 4)
__global__ void ln_kernel(const float* __restrict__ in, const float* __restrict__ g,
                          const float* __restrict__ b, short* __restrict__ out) {
  const int row = blockIdx.x;
  const int tid = threadIdx.x;
  const float4 v = ((const float4*)(in + (size_t)row * 1024))[tid];
  float s = v.x + v.y + v.z + v.w;
  float s2 = v.x * v.x + v.y * v.y + v.z * v.z + v.w * v.w;
#pragma unroll
  for (int off = 1; off < 64; off <<= 1) {
    s += __shfl_xor(s, off);
    s2 += __shfl_xor(s2, off);
  }
  __shared__ float ps[4], pq[4];
  const int w = tid >> 6, lane = tid & 63;
  if (lane == 0) { ps[w] = s; pq[w] = s2; }
  __syncthreads();
  s = ps[0] + ps[1] + ps[2] + ps[3];
  s2 = pq[0] + pq[1] + pq[2] + pq[3];
  const float mu = s * (1.f / 1024.f);
  const float rs = rsqrtf(s2 * (1.f / 1024.f) - mu * mu + 1e-5f);
  const float4 gg = ((const float4*)g)[tid];
  const float4 bb = ((const float4*)b)[tid];
  short4 o4;
  o4.x = f2bf((v.x - mu) * rs * gg.x + bb.x);
  o4.y = f2bf((v.y - mu) * rs * gg.y + bb.y);
  o4.z = f2bf((v.z - mu) * rs * gg.z + bb.z);
  o4.w = f2bf((v.w - mu) * rs * gg.w + bb.w);
  ((short4*)(out + (size_t)row * 1024))[tid] = o4;
}

// ---------------------------------------------------------------- GEMM epi
enum { EPI_Q = 0, EPI_PLAIN = 1, EPI_BIAS_RESID_F32 = 2, EPI_BIAS_SILU = 3, EPI_PARTIAL = 4 };

DEV void epi_store(int EPI, size_t idx, int cg, float v, const float* bias,
                   const float* resid, float scale, short* outb, float* outf) {
  if (EPI == EPI_Q) {
    outb[idx] = f2bf(v * scale);
  } else if (EPI == EPI_PLAIN) {
    outb[idx] = f2bf(v);
  } else if (EPI == EPI_BIAS_RESID_F32) {
    outf[idx] = v + bias[cg] + resid[idx];
  } else if (EPI == EPI_BIAS_SILU) {
    const float u = v + bias[cg];
    outb[idx] = f2bf(u / (1.f + __expf(-u)));
  } else {  // EPI_PARTIAL
    outf[idx] = v;
  }
}

// ---------------------------------------------------------------- gemm core
// BM=BN=256, BK=64, 512 thr, waves 2Mx4N (per-wave 128x64 out).
// 8 phases / 2 K-tiles, 16 MFMA each. MFMA_Q(mq,nq) = C-QUADRANT indices
// (NOT K-tile); both K-tiles accumulate into the same acc[8][4].
template <int EPI>
DEV void gemm_core(const short* __restrict__ A, const short* __restrict__ Bt,
                   int lda, int ldb, int k0, int nit, int N, int nbx, int nwg, int id,
                   const float* __restrict__ bias, const float* __restrict__ resid,
                   float scale, short* __restrict__ outb, float* __restrict__ outf,
                   char* Albase, char* Blbase) {
  const int tid = threadIdx.x;
  const int lane = tid & 63, w = tid >> 6;
  const int wr = w >> 2, wc = w & 3;
  const int lg = lane >> 4, lr = lane & 15;
  const int swz = (id & 7) * (nwg >> 3) + (id >> 3);  // nwg % 8 == 0 (bijective)
  const int bx = swz % nbx, by = swz / nbx;
  const int row0 = by * 256, col0 = bx * 256;
  const int rsw = (lr & 7) << 4;
  const int scb = (((tid & 7) ^ ((tid >> 3) & 7)) << 4);  // pre-swizzled source
  const size_t lda2 = (size_t)lda * 2, ldb2 = (size_t)ldb * 2;
  const char* Asrc = (const char*)A + (size_t)(row0 + (tid >> 3)) * lda2 + (size_t)k0 * 2 + scb;
  const char* Bsrc = (const char*)Bt + (size_t)(col0 + (tid >> 3)) * ldb2 + (size_t)k0 * 2 + scb;
  char* Adst = Albase + w * 1024;
  char* Bdst = Blbase + w * 1024;

#define STG_A(t, h) do { \
    gload_lds16(Asrc + (size_t)((h) * 128) * lda2 + (size_t)(t) * 128, \
                Adst + (((t) & 1) * 2 + (h)) * 16384); \
    gload_lds16(Asrc + (size_t)((h) * 128 + 64) * lda2 + (size_t)(t) * 128, \
                Adst + (((t) & 1) * 2 + (h)) * 16384 + 8192); } while (0)
#define STG_B(t, h) do { \
    gload_lds16(Bsrc + (size_t)((h) * 128) * ldb2 + (size_t)(t) * 128, \
                Bdst + (((t) & 1) * 2 + (h)) * 16384); \
    gload_lds16(Bsrc + (size_t)((h) * 128 + 64) * ldb2 + (size_t)(t) * 128, \
                Bdst + (((t) & 1) * 2 + (h)) * 16384 + 8192); } while (0)
#define RD_A(buf, mq, mi, ks) (*(const bf16x8*)(Albase + ((buf) * 2 + wr) * 16384 + \
    ((mq) * 64 + (mi) * 16 + lr) * 128 + (((ks) * 64 + lg * 16) ^ rsw)))
#define RD_B(buf, nq, ni, ks) (*(const bf16x8*)(Blbase + ((buf) * 2 + (wc >> 1)) * 16384 + \
    ((wc & 1) * 64 + (nq) * 32 + (ni) * 16 + lr) * 128 + (((ks) * 64 + lg * 16) ^ rsw)))
#define MFMA_Q(mq, nq, BF) do { \
    __builtin_amdgcn_s_setprio(1); \
    _Pragma("unroll") for (int mi_ = 0; mi_ < 4; ++mi_) \
    _Pragma("unroll") for (int ni_ = 0; ni_ < 2; ++ni_) \
    _Pragma("unroll") for (int ks_ = 0; ks_ < 2; ++ks_) \
      acc[(mq) * 4 + mi_][(nq) * 2 + ni_] = __builtin_amdgcn_mfma_f32_16x16x32_bf16( \
          af[mi_][ks_], BF[ni_][ks_], acc[(mq) * 4 + mi_][(nq) * 2 + ni_], 0, 0, 0); \
    __builtin_amdgcn_s_setprio(0); } while (0)
#define PH_ENTRY() do { __builtin_amdgcn_sched_barrier(0); __builtin_amdgcn_s_barrier(); \
    __builtin_amdgcn_sched_barrier(0); } while (0)
#define PH_LGKM() do { asm volatile("s_waitcnt lgkmcnt(0)" ::: "memory"); \
    __builtin_amdgcn_sched_barrier(0); } while (0)

  // prologue: tiles 0 (buf0) and 1 (buf1); 16 loads outstanding
  STG_B(0, 0); STG_B(0, 1); STG_A(0, 0); STG_A(0, 1);
  STG_B(1, 0); STG_B(1, 1); STG_A(1, 0); STG_A(1, 1);

  f32x4 acc[8][4] = {};
  bf16x8 af[4][2], b0[2][2], b1[2][2];

#pragma unroll 1
  for (int i = 0; i < nit; ++i) {
    const int t2 = 2 * i + 2, t3 = 2 * i + 3;
    const bool pf = (i + 1 < nit);
    // ---- P1 (buf0, quad mq0,nq0): tile t0=2i resident for all waves
    asm volatile("s_waitcnt vmcnt(8)" ::: "memory");
    PH_ENTRY();  // barrier AFTER vmcnt, BEFORE reads
#pragma unroll
    for (int mi = 0; mi < 4; ++mi) { af[mi][0] = RD_A(0, 0, mi, 0); af[mi][1] = RD_A(0, 0, mi, 1); }
#pragma unroll
    for (int ni = 0; ni < 2; ++ni) { b0[ni][0] = RD_B(0, 0, ni, 0); b0[ni][1] = RD_B(0, 0, ni, 1); }
    PH_LGKM();
    MFMA_Q(0, 0, b0);
    // ---- P2 (buf0, quad mq0,nq1)
    PH_ENTRY();
#pragma unroll
    for (int ni = 0; ni < 2; ++ni) { b1[ni][0] = RD_B(0, 1, ni, 0); b1[ni][1] = RD_B(0, 1, ni, 1); }
    PH_LGKM();
    MFMA_Q(0, 1, b1);
    // ---- P3 (buf0, quad mq1,nq0): B(t0) dead -> stage B(t2)
    PH_ENTRY();
#pragma unroll
    for (int mi = 0; mi < 4; ++mi) { af[mi][0] = RD_A(0, 1, mi, 0); af[mi][1] = RD_A(0, 1, mi, 1); }
    if (pf) { STG_B(t2, 0); STG_B(t2, 1); }
    PH_LGKM();
    MFMA_Q(1, 0, b0);
    // ---- P4 (buf0, quad mq1,nq1): A(t0) dead -> stage A(t2)
    PH_ENTRY();
    if (pf) { STG_A(t2, 0); STG_A(t2, 1); }
    PH_LGKM();
    MFMA_Q(1, 1, b1);
    // ---- P5 (buf1, quad mq0,nq0): tile t1=2i+1 resident
    if (pf) asm volatile("s_waitcnt vmcnt(8)" ::: "memory");
    else    asm volatile("s_waitcnt vmcnt(0)" ::: "memory");
    PH_ENTRY();
#pragma unroll
    for (int mi = 0; mi < 4; ++mi) { af[mi][0] = RD_A(1, 0, mi, 0); af[mi][1] = RD_A(1, 0, mi, 1); }
#pragma unroll
    for (int ni = 0; ni < 2; ++ni) { b0[ni][0] = RD_B(1, 0, ni, 0); b0[ni][1] = RD_B(1, 0, ni, 1); }
    PH_LGKM();
    MFMA_Q(0, 0, b0);  // FIXED: accumulate into quad (0,0), not acc[8..]
    // ---- P6 (buf1, quad mq0,nq1)
    PH_ENTRY();
#pragma unroll
    for (int ni = 0; ni < 2; ++ni) { b1[ni][0] = RD_B(1, 1, ni, 0); b1[ni][1] = RD_B(1, 1, ni, 1); }
    PH_LGKM();
    MFMA_Q(0, 1, b1);  // FIXED
    // ---- P7 (buf1, quad mq1,nq0): stage B(t3)
    PH_ENTRY();
#pragma unroll
    for (int mi = 0; mi < 4; ++mi) { af[mi][0] = RD_A(1, 1, mi, 0); af[mi][1] = RD_A(1, 1, mi, 1); }
    if (pf) { STG_B(t3, 0); STG_B(t3, 1); }
    PH_LGKM();
    MFMA_Q(1, 0, b0);  // FIXED
    // ---- P8 (buf1, quad mq1,nq1): stage A(t3)
    PH_ENTRY();
    if (pf) { STG_A(t3, 0); STG_A(t3, 1); }
    PH_LGKM();
    MFMA_Q(1, 1, b1);  // FIXED
  }
#undef STG_A
#undef STG_B
#undef RD_A
#undef RD_B
#undef MFMA_Q
#undef PH_ENTRY
#undef PH_LGKM
  // acc[mq*4+mi][nq*2+ni] -> row = wr*128+mq*64+mi*16+lg*4+r, col = wc*64+nq*32+ni*16+lr
#pragma unroll
  for (int mi = 0; mi < 8; ++mi) {
#pragma unroll
    for (int nj = 0; nj < 4; ++nj) {
      const int cg = col0 + wc * 64 + (nj >> 1) * 32 + (nj & 1) * 16 + lr;
#pragma unroll
      for (int r = 0; r < 4; ++r) {
        const int rg = row0 + wr * 128 + (mi >> 2) * 64 + (mi & 3) * 16 + lg * 4 + r;
        epi_store(EPI, (size_t)rg * N + cg, cg, acc[mi][nj][r], bias, resid, scale, outb, outf);
      }
    }
  }
}

template <int EPI>
__launch_bounds__(512, 2)
__global__ void gemm256k(const short* __restrict__ A, const short* __restrict__ Bt,
                         int lda, int ldb, int ksub, int N, int nbx,
                         const float* __restrict__ bias, const float* __restrict__ resid,
                         float scale, short* __restrict__ outb, float* __restrict__ outf) {
  __shared__ short Al[2][2][128 * 64];
  __shared__ short Bl[2][2][128 * 64];
  const int k0 = blockIdx.y * ksub;
  float* of = outf;
  if (EPI == EPI_PARTIAL) of = outf + (size_t)blockIdx.y * 8192 * 1024;
  gemm_core<EPI>(A, Bt, lda, ldb, k0, ksub >> 7, N, nbx, gridDim.x, blockIdx.x,
                 bias, resid, scale, outb, of, (char*)&Al[0][0][0], (char*)&Bl[0][0][0]);
}

// ---------------------------------------------------------------- split-K reduce
__launch_bounds__(256, 8)
__global__ void splitk_reduce(const float* __restrict__ p0, const float* __restrict__ p1,
                              const float* __restrict__ bias, const float* __restrict__ resid,
                              float* __restrict__ out) {
  const size_t i = (size_t)blockIdx.x * 256 + threadIdx.x;  // float4 index
  const int col4 = (int)(i & 255);
  const float4 a = ((const float4*)p0)[i];
  const float4 b = ((const float4*)p1)[i];
  const float4 c = ((const float4*)resid)[i];
  const float4 g = ((const float4*)bias)[col4];
  float4 o;
  o.x = a.x + b.x + c.x + g.x;
  o.y = a.y + b.y + c.y + g.y;
  o.z = a.z + b.z + c.z + g.z;
  o.w = a.w + b.w + c.w + g.w;
  ((float4*)out)[i] = o;
}

// ---------------------------------------------------------------- attention
__launch_bounds__(512, 4)
__global__ void attn_kernel(const short* __restrict__ Qg, const short* __restrict__ KVg,
                            const short* __restrict__ Vtg, short* __restrict__ AO) {
  __shared__ short Kl[2][64 * 64];
  __shared__ short Vl[2][64 * 64];
  __shared__ short Pl[8][32 * 64];
  const int tid = threadIdx.x;
  const int lane = tid & 63, w = tid >> 6;
  const int lg = lane >> 4, lr = lane & 15;

  const int id = blockIdx.x;  // 512 blocks
  const int xcd = id & 7, j = id >> 3;
  const int bh = xcd * 8 + (j & 7);
  const int qblk = j >> 3;
  const int b = bh >> 4, h = bh & 15;
  const int q0 = qblk * 256 + w * 32;

  bf16x8 qf[2][2];
#pragma unroll
  for (int qb = 0; qb < 2; ++qb) {
    const short* qp = Qg + ((size_t)b * 2048 + q0 + qb * 16 + lr) * 1024 + h * 64 + lg * 8;
    qf[qb][0] = *(const bf16x8*)qp;
    qf[qb][1] = *(const bf16x8*)(qp + 32);
  }

  const int srow = lane >> 3;
  const int scb = ((lane & 7) << 4) ^ (srow << 4);
  // K rows in fused KV buffer: row stride 2048 elements (4096 B), K at cols 0..1023
  const char* Ks = (const char*)KVg + ((size_t)b * 2048 + w * 8 + srow) * 4096 + h * 128 + scb;
  const char* Vs = (const char*)Vtg + ((size_t)bh * 64 + w * 8 + srow) * 4096 + scb;
  char* KB[2] = {(char*)&Kl[0][0] + w * 1024, (char*)&Kl[1][0] + w * 1024};
  char* VB[2] = {(char*)&Vl[0][0] + w * 1024, (char*)&Vl[1][0] + w * 1024};

  f32x4 acc[2][4] = {};
  float m_run[2] = {-1e30f, -1e30f};
  float l_run[2] = {0.f, 0.f};
  char* Pw = (char*)&Pl[w][0];
  const int sw = (lr & 7) << 4;

  gload_lds16(Ks, KB[0]);
  gload_lds16(Vs, VB[0]);
  __syncthreads();
  int buf = 0;

  for (int kv0 = 0; kv0 < 2048; kv0 += 64) {
    if (kv0 + 64 < 2048) {
      gload_lds16(Ks + (size_t)(kv0 + 64) * 4096, KB[buf ^ 1]);
      gload_lds16(Vs + (size_t)(kv0 + 64) * 2, VB[buf ^ 1]);
    }
    f32x4 st[4][2];
#pragma unroll
    for (int t = 0; t < 4; ++t) {
      const char* kb = (const char*)&Kl[buf][0] + (t * 16 + lr) * 128;
      const bf16x8 kf0 = *(const bf16x8*)(kb + ((lg * 16) ^ sw));
      const bf16x8 kf1 = *(const bf16x8*)(kb + ((64 + lg * 16) ^ sw));
#pragma unroll
      for (int qb = 0; qb < 2; ++qb) {
        f32x4 z = {};
        z = __builtin_amdgcn_mfma_f32_16x16x32_bf16(kf0, qf[qb][0], z, 0, 0, 0);
        z = __builtin_amdgcn_mfma_f32_16x16x32_bf16(kf1, qf[qb][1], z, 0, 0, 0);
        st[t][qb] = z;
      }
    }
#pragma unroll
    for (int qb = 0; qb < 2; ++qb) {
      float smax = st[0][qb][0];
#pragma unroll
      for (int t = 0; t < 4; ++t)
#pragma unroll
        for (int r = 0; r < 4; ++r) smax = fmaxf(smax, st[t][qb][r]);
      smax = fmaxf(smax, __shfl_xor(smax, 16));
      smax = fmaxf(smax, __shfl_xor(smax, 32));
      float m_use = m_run[qb];
      if (!__all(smax - m_use <= 8.f)) {
        const float mnew = fmaxf(m_use, smax);
        const float alpha = __builtin_amdgcn_exp2f(m_use - mnew);
        m_run[qb] = mnew;
        m_use = mnew;
        l_run[qb] *= alpha;
        float ar[4];
#pragma unroll
        for (int r = 0; r < 4; ++r) ar[r] = __shfl(alpha, lg * 4 + r);
#pragma unroll
        for (int dt = 0; dt < 4; ++dt)
#pragma unroll
          for (int r = 0; r < 4; ++r) acc[qb][dt][r] *= ar[r];
      }
      float rsum = 0.f;
#pragma unroll
      for (int t = 0; t < 4; ++t) {
        bf16x4 pk;
        float ps = 0.f;
#pragma unroll
        for (int r = 0; r < 4; ++r) {
          const float p = __builtin_amdgcn_exp2f(st[t][qb][r] - m_use);
          ps += p;
          pk[r] = (__bf16)p;
        }
        rsum += ps;
        *(bf16x4*)(Pw + (qb * 16 + lr) * 128 + ((t * 32 + lg * 8) ^ sw)) = pk;
      }
      rsum += __shfl_xor(rsum, 16);
      rsum += __shfl_xor(rsum, 32);
      l_run[qb] += rsum;
    }
#pragma unroll
    for (int c = 0; c < 2; ++c) {
      const bf16x8 pf0 = *(const bf16x8*)(Pw + lr * 128 + ((c * 64 + lg * 16) ^ sw));
      const bf16x8 pf1 = *(const bf16x8*)(Pw + (16 + lr) * 128 + ((c * 64 + lg * 16) ^ sw));
#pragma unroll
      for (int dt = 0; dt < 4; ++dt) {
        const bf16x8 vf = *(const bf16x8*)((const char*)&Vl[buf][0] + (dt * 16 + lr) * 128 +
                                           ((c * 64 + lg * 16) ^ sw));
        acc[0][dt] = __builtin_amdgcn_mfma_f32_16x16x32_bf16(pf0, vf, acc[0][dt], 0, 0, 0);
        acc[1][dt] = __builtin_amdgcn_mfma_f32_16x16x32_bf16(pf1, vf, acc[1][dt], 0, 0, 0);
      }
    }
    __syncthreads();
    buf ^= 1;
  }
#pragma unroll
  for (int qb = 0; qb < 2; ++qb) {
    const float linv = 1.f / l_run[qb];
    float lv[4];
#pragma unroll
    for (int r = 0; r < 4; ++r) lv[r] = __shfl(linv, lg * 4 + r);
#pragma unroll
    for (int dt = 0; dt < 4; ++dt)
#pragma unroll
      for (int r = 0; r < 4; ++r)
        AO[((size_t)b * 2048 + q0 + qb * 16 + lg * 4 + r) * 1024 + h * 64 + dt * 16 + lr] =
            f2bf(acc[qb][dt][r] * lv[r]);
  }
}

// ---------------------------------------------------------------- launch
extern "C" void kernel_launch(void* const* d_in, const int* in_sizes, int n_in,
                              void* d_out, int out_size, void* d_ws, size_t ws_size,
                              hipStream_t stream) {
  const float* x   = (const float*)d_in[0];
  const float* ctx = (const float*)d_in[1];
  const float* Wq  = (const float*)d_in[2];
  const float* Wk  = (const float*)d_in[3];
  const float* Wv  = (const float*)d_in[4];
  const float* Wo  = (const float*)d_in[5];
  const float* bo  = (const float*)d_in[6];
  const float* g_q = (const float*)d_in[7];
  const float* b_q = (const float*)d_in[8];
  const float* g_k = (const float*)d_in[9];
  const float* b_k = (const float*)d_in[10];
  const float* g_m = (const float*)d_in[11];
  const float* b_m = (const float*)d_in[12];
  const float* W1  = (const float*)d_in[13];
  const float* b1  = (const float*)d_in[14];
  const float* W2  = (const float*)d_in[15];
  const float* b2  = (const float*)d_in[16];
  float* out = (float*)d_out;

  // workspace carve (order matters: Qb,KVb,Vts contiguous for split-K aliasing)
  short* p = (short*)d_ws;
  short* xn   = p; p += (size_t)8192 * 1024;
  short* cn   = p; p += (size_t)8192 * 1024;
  short* Qb   = p; p += (size_t)8192 * 1024;
  short* KVb  = p; p += (size_t)8192 * 2048;
  short* Vts  = p; p += (size_t)8192 * 1024;
  short* AO   = p; p += (size_t)8192 * 1024;
  short* hn   = p; p += (size_t)8192 * 1024;
  short* hm   = p; p += (size_t)8192 * 4096;
  short* WqT  = p; p += (size_t)1024 * 1024;
  short* WkvT = p; p += (size_t)2048 * 1024;
  short* WoT  = p; p += (size_t)1024 * 1024;
  short* W1T  = p; p += (size_t)1024 * 4096;
  short* W2T  = p; p += (size_t)4096 * 1024;
  float* x2   = (float*)p;  // 8192*1024 fp32
  // split-K partials alias dead-by-then Qb..Vts region (64 MB contiguous)
  float* part = (float*)Qb;

  const dim3 tb(32, 8);
  transpose_f32_bf16<<<dim3(32, 32), tb, 0, stream>>>(Wq, WqT, 1024, 1024);
  transpose_f32_bf16<<<dim3(32, 32), tb, 0, stream>>>(Wk, WkvT, 1024, 1024);
  transpose_f32_bf16<<<dim3(32, 32), tb, 0, stream>>>(Wv, WkvT + (size_t)1024 * 1024, 1024, 1024);
  transpose_f32_bf16<<<dim3(32, 32), tb, 0, stream>>>(Wo, WoT, 1024, 1024);
  transpose_f32_bf16<<<dim3(128, 32), tb, 0, stream>>>(W1, W1T, 1024, 4096);
  transpose_f32_bf16<<<dim3(32, 128), tb, 0, stream>>>(W2, W2T, 4096, 1024);

  ln_kernel<<<8192, 256, 0, stream>>>(x, g_q, b_q, xn);
  ln_kernel<<<8192, 256, 0, stream>>>(ctx, g_k, b_k, cn);

  const float qscale = 0.125f * 1.44269504088896340736f;  // 1/sqrt(64) * log2(e)
  // Q: M=8192,N=1024,K=1024 -> 128 blocks
  gemm256k<EPI_Q><<<dim3(128, 1), 512, 0, stream>>>(xn, WqT, 1024, 1024, 1024, 1024, 4,
                                                    nullptr, nullptr, qscale, Qb, nullptr);
  // K+V fused: N=2048 -> 256 blocks
  gemm256k<EPI_PLAIN><<<dim3(256, 1), 512, 0, stream>>>(cn, WkvT, 1024, 1024, 1024, 2048, 8,
                                                        nullptr, nullptr, 0.f, KVb, nullptr);

  transpose_v<<<dim3(64, 2, 64), tb, 0, stream>>>(KVb, Vts);

  attn_kernel<<<512, 512, 0, stream>>>(Qb, KVb, Vts, AO);

  gemm256k<EPI_BIAS_RESID_F32><<<dim3(128, 1), 512, 0, stream>>>(AO, WoT, 1024, 1024, 1024, 1024, 4,
                                                                 bo, x, 0.f, nullptr, x2);

  ln_kernel<<<8192, 256, 0, stream>>>(x2, g_m, b_m, hn);

  // W1: N=4096 -> 512 blocks
  gemm256k<EPI_BIAS_SILU><<<dim3(512, 1), 512, 0, stream>>>(hn, W1T, 1024, 1024, 1024, 4096, 16,
                                                            b1, nullptr, 0.f, hm, nullptr);
  // W2: split-K=2, grid 128x2, partials -> reduce
  gemm256k<EPI_PARTIAL><<<dim3(128, 2), 512, 0, stream>>>(hm, W2T, 4096, 4096, 2048, 1024, 4,
                                                          nullptr, nullptr, 0.f, nullptr, part);
  splitk_reduce<<<8192, 256, 0, stream>>>(part, part + (size_t)8192 * 1024, b2, x2, out);
}